// Round 9
// baseline (263.495 us; speedup 1.0000x reference)
//
#include <hip/hip_runtime.h>

#define NN 4096
#define DD 64
#define KK 5
#define NBINS 1024
#define BINMUL 2.0f     // fallback hist bin width 0.5 over [0, 512)
#define RMED 8388607u   // (NN*NN - 1) / 2
#define ROWB 80         // padded LDS row stride (bytes): 5*row mod 8 spreads slots
#define TILEB (128 * ROWB)   // 10240 B per tile, 4 tiles = 40960 B
#define MBUF_FLOATS 10240u   // gather buffer capacity (reuses 40KB tiles)

typedef short short8 __attribute__((ext_vector_type(8)));
typedef float f32x4 __attribute__((ext_vector_type(4)));

struct Ctrl {
  unsigned wcount;   // window-gathered count (MODE 0)
  unsigned wover;    // LDS gather overflow flag
  unsigned below;    // exact count of d < loE (MODE 0)
  unsigned gcount;   // fallback-gathered count (MODE 1)
  unsigned sel_bin;  // fallback selected bin
  unsigned rank;     // fallback rank within sel_bin
  unsigned spref;    // radix prefix
  unsigned srank;    // remaining radix rank
  unsigned use_pow;  // kernel_scales == [0.5,1,2,4,8]
  float median;
  float c2;          // base*0.5*log2(e)
  float scales[KK];
};

__device__ inline bool window_ok(const Ctrl* c, unsigned cap) {
  return (c->wover == 0u) && (c->wcount <= cap) && (c->below <= RMED) &&
         ((RMED - c->below) < c->wcount);
}
__device__ inline float fast_exp2(float x) {
  float r;
  asm("v_exp_f32 %0, %1" : "=v"(r) : "v"(x));
  return r;
}
__device__ inline unsigned short bf16_rn(float f) {
  unsigned u = __float_as_uint(f);
  return (unsigned short)((u + 0x7FFFu + ((u >> 16) & 1u)) >> 16);
}
__device__ inline float bf16_val(unsigned short h) {
  return __uint_as_float(((unsigned)h) << 16);
}

// ---------------- fused split (f32 -> bf16 hi/lo) + row norms ----------------
__global__ void __launch_bounds__(256)
splitnorms_kernel(const float* __restrict__ x, const float* __restrict__ y,
                  short* __restrict__ xhi, short* __restrict__ xlo,
                  short* __restrict__ yhi, short* __restrict__ ylo,
                  float* __restrict__ xn, float* __restrict__ yn) {
  unsigned g = blockIdx.x * 256u + threadIdx.x;  // float4 id 0..131071
  const float* src; short *dhi, *dlo; float* nrm; unsigned local;
  if (g < 65536u) { src = x; dhi = xhi; dlo = xlo; nrm = xn; local = g; }
  else { src = y; dhi = yhi; dlo = ylo; nrm = yn; local = g - 65536u; }
  float4 v = *(const float4*)(src + (size_t)local * 4);
  unsigned short h0 = bf16_rn(v.x), h1 = bf16_rn(v.y), h2 = bf16_rn(v.z), h3 = bf16_rn(v.w);
  unsigned short l0 = bf16_rn(v.x - bf16_val(h0));
  unsigned short l1 = bf16_rn(v.y - bf16_val(h1));
  unsigned short l2 = bf16_rn(v.z - bf16_val(h2));
  unsigned short l3 = bf16_rn(v.w - bf16_val(h3));
  unsigned long long H = (unsigned long long)h0 | ((unsigned long long)h1 << 16) |
                         ((unsigned long long)h2 << 32) | ((unsigned long long)h3 << 48);
  unsigned long long L = (unsigned long long)l0 | ((unsigned long long)l1 << 16) |
                         ((unsigned long long)l2 << 32) | ((unsigned long long)l3 << 48);
  *(unsigned long long*)((char*)dhi + (size_t)local * 8) = H;
  *(unsigned long long*)((char*)dlo + (size_t)local * 8) = L;
  float part = v.x * v.x;
  part = fmaf(v.y, v.y, part);
  part = fmaf(v.z, v.z, part);
  part = fmaf(v.w, v.w, part);
#pragma unroll
  for (int off = 1; off < 16; off <<= 1) part += __shfl_xor(part, off);
  if ((threadIdx.x & 15) == 0) nrm[local >> 4] = part;
}

// ---------------- MFMA pair-tile kernel ----------------
// 128x128 tile, 4 waves of 64x64, bf16x2 split (hihi + hilo + lohi), two K-phases.
// MODE 0: below-count + window gather  (common path)
// MODE 3: fallback full hist + fused bin select (early-exit if window ok)
// MODE 1: fallback gather of sel_bin (early-exit if window ok)
// MODE 2: kernel sums (z: 0=xx 1=yy 2=zz)
template <int MODE>
__global__ void __launch_bounds__(256)
pair_kernel(const short* __restrict__ xhi, const short* __restrict__ xlo,
            const short* __restrict__ yhi, const short* __restrict__ ylo,
            const float* __restrict__ xn, const float* __restrict__ yn,
            unsigned* __restrict__ hist, Ctrl* __restrict__ ctrl,
            float* __restrict__ buf, double* __restrict__ S,
            unsigned* __restrict__ tick, float loE, float hiE, unsigned cap) {
  if (MODE == 1 || MODE == 3) {
    if (window_ok(ctrl, cap)) return;  // common path: nothing to do
  }
  __shared__ __align__(16) char smem[4 * TILEB];  // 40KB
  __shared__ unsigned bcnt, gbase, lastflag;

  int t = threadIdx.x;
  int sel = (MODE == 2) ? blockIdx.z : 0;
  const char* Ah = (const char*)((sel == 1) ? yhi : xhi);
  const char* Al = (const char*)((sel == 1) ? ylo : xlo);
  const char* Bh = (const char*)((sel == 0) ? xhi : yhi);
  const char* Bl = (const char*)((sel == 0) ? xlo : ylo);
  const float* An = (sel == 1) ? yn : xn;
  const float* Bn = (sel == 0) ? xn : yn;
  int rowBase = blockIdx.y * 128, colBase = blockIdx.x * 128;
  const char* gsrc0 = Ah + (size_t)rowBase * 128;
  const char* gsrc1 = Al + (size_t)rowBase * 128;
  const char* gsrc2 = Bh + (size_t)colBase * 128;
  const char* gsrc3 = Bl + (size_t)colBase * 128;

  int lane = t & 63, wid = t >> 6;
  int wr = (wid >> 1) * 64, wc = (wid & 1) * 64;
  int lrow = lane & 15;
  int koff = (lane >> 4) * 16;  // byte offset of this lane's 8-bf16 fragment

  f32x4 acc[4][4] = {};
#pragma unroll
  for (int p = 0; p < 2; ++p) {
    short8 rg[8];
#pragma unroll
    for (int i = 0; i < 8; ++i) {
      int c = t + i * 256;
      const char* gs = (c < 512) ? gsrc0 : (c < 1024) ? gsrc1 : (c < 1536) ? gsrc2 : gsrc3;
      int cr = c & 511, row = cr >> 2, kc = cr & 3;
      rg[i] = *(const short8*)(gs + (size_t)row * 128 + p * 64 + kc * 16);
    }
    if (p) __syncthreads();  // phase-0 fragment reads complete before overwrite
#pragma unroll
    for (int i = 0; i < 8; ++i) {
      int c = t + i * 256;
      int tile = c >> 9, cr = c & 511, row = cr >> 2, kc = cr & 3;
      *(short8*)(smem + tile * TILEB + row * ROWB + kc * 16) = rg[i];
    }
    __syncthreads();
    short8 bh[4], bl[4];
#pragma unroll
    for (int n = 0; n < 4; ++n) {
      int off = (wc + n * 16 + lrow) * ROWB + koff;
      bh[n] = *(const short8*)(smem + 2 * TILEB + off);
      bl[n] = *(const short8*)(smem + 3 * TILEB + off);
    }
#pragma unroll
    for (int m = 0; m < 4; ++m) {
      int off = (wr + m * 16 + lrow) * ROWB + koff;
      short8 ah = *(const short8*)(smem + off);
      short8 al = *(const short8*)(smem + TILEB + off);
#pragma unroll
      for (int n = 0; n < 4; ++n) {
        acc[m][n] = __builtin_amdgcn_mfma_f32_16x16x32_bf16(ah, bh[n], acc[m][n], 0, 0, 0);
        acc[m][n] = __builtin_amdgcn_mfma_f32_16x16x32_bf16(ah, bl[n], acc[m][n], 0, 0, 0);
        acc[m][n] = __builtin_amdgcn_mfma_f32_16x16x32_bf16(al, bh[n], acc[m][n], 0, 0, 0);
      }
    }
  }
  __syncthreads();  // all fragment reads done; smem reusable below

  // C/D map (HW-verified m89): col = lane&15, row = (lane>>4)*4 + reg
  float anv[16], bnv[4];
#pragma unroll
  for (int m = 0; m < 4; ++m)
#pragma unroll
    for (int r = 0; r < 4; ++r)
      anv[m * 4 + r] = An[rowBase + wr + m * 16 + (lane >> 4) * 4 + r];
#pragma unroll
  for (int n = 0; n < 4; ++n) bnv[n] = Bn[colBase + wc + n * 16 + lrow];

  if (MODE == 0) {
    float* mbuf = (float*)smem;
    if (t == 0) bcnt = 0;
    __syncthreads();
    int below = 0;
#pragma unroll
    for (int m = 0; m < 4; ++m)
#pragma unroll
      for (int n = 0; n < 4; ++n)
#pragma unroll
        for (int r = 0; r < 4; ++r) {
          float d = (anv[m * 4 + r] + bnv[n]) - 2.0f * acc[m][n][r];
          below += (d < loE) ? 1 : 0;
          if (d >= loE && d < hiE) {
            unsigned idx = atomicAdd(&bcnt, 1u);
            if (idx < MBUF_FLOATS) mbuf[idx] = d - 100.0f;  // exact (d in [100,200])
            else ctrl->wover = 1u;
          }
        }
#pragma unroll
    for (int off = 32; off > 0; off >>= 1) below += __shfl_down(below, off);
    if (lane == 0) atomicAdd(&ctrl->below, (unsigned)below);
    __syncthreads();
    unsigned cnt = min(bcnt, MBUF_FLOATS);
    if (t == 0) gbase = atomicAdd(&ctrl->wcount, cnt);
    __syncthreads();
    for (unsigned i = t; i < cnt; i += 256) {
      unsigned gi = gbase + i;
      if (gi < cap) buf[gi] = mbuf[i];
    }
  }

  if (MODE == 3) {  // fallback: full histogram + fused bin select
    unsigned* h = (unsigned*)smem;
    for (int i = t; i < NBINS; i += 256) h[i] = 0;
    if (t == 0) lastflag = 0;
    __syncthreads();
#pragma unroll
    for (int m = 0; m < 4; ++m)
#pragma unroll
      for (int n = 0; n < 4; ++n)
#pragma unroll
        for (int r = 0; r < 4; ++r) {
          float d = (anv[m * 4 + r] + bnv[n]) - 2.0f * acc[m][n][r];
          int b = (int)(d * BINMUL);
          b = min(max(b, 0), NBINS - 1);
          atomicAdd(&h[b], 1u);
        }
    __syncthreads();
    for (int i = t; i < NBINS; i += 256)
      if (h[i]) atomicAdd(&hist[i], h[i]);
    __threadfence();
    if (t == 0)
      lastflag = (atomicAdd(&tick[4], 1u) == gridDim.x * gridDim.y - 1u) ? 1u : 0u;
    __syncthreads();
    if (!lastflag) return;
    // last block: select bin of rank RMED (L2-forced reads)
    unsigned* ps = h + NBINS;  // scratch (smem has room: 10240 u32 total)
    unsigned loc[4]; unsigned s = 0;
#pragma unroll
    for (int i = 0; i < 4; ++i) { loc[i] = atomicAdd(&hist[t * 4 + i], 0u); s += loc[i]; }
    ps[t] = s;
    __syncthreads();
    for (int off = 1; off < 256; off <<= 1) {
      unsigned v = ps[t];
      unsigned add = (t >= off) ? ps[t - off] : 0u;
      __syncthreads();
      ps[t] = v + add;
      __syncthreads();
    }
    unsigned incl = ps[t], excl = incl - s;
    if (RMED >= excl && RMED < incl) {
      unsigned rank = RMED - excl;
      int bsel = -1;
#pragma unroll
      for (int i = 0; i < 4; ++i) {
        if (bsel < 0) {
          if (rank < loc[i]) bsel = t * 4 + i;
          else rank -= loc[i];
        }
      }
      ctrl->sel_bin = (unsigned)bsel;
      ctrl->rank = rank;
    }
  }

  if (MODE == 1) {  // fallback gather of sel_bin
    unsigned sb = ctrl->sel_bin;
    float* mbuf = (float*)smem;
    if (t == 0) bcnt = 0;
    __syncthreads();
#pragma unroll
    for (int m = 0; m < 4; ++m)
#pragma unroll
      for (int n = 0; n < 4; ++n)
#pragma unroll
        for (int r = 0; r < 4; ++r) {
          float d = (anv[m * 4 + r] + bnv[n]) - 2.0f * acc[m][n][r];
          int b = (int)(d * BINMUL);
          b = min(max(b, 0), NBINS - 1);
          if ((unsigned)b == sb) {
            unsigned idx = atomicAdd(&bcnt, 1u);
            if (idx < MBUF_FLOATS) mbuf[idx] = d - 100.0f;
          }
        }
    __syncthreads();
    unsigned cnt = min(bcnt, MBUF_FLOATS);
    if (t == 0) gbase = atomicAdd(&ctrl->gcount, cnt);
    __syncthreads();
    for (unsigned i = t; i < cnt; i += 256) {
      unsigned gi = gbase + i;
      if (gi < cap) buf[gi] = mbuf[i];
    }
  }

  if (MODE == 2) {
    float s = 0.f;
    if (ctrl->use_pow) {
      float c2 = ctrl->c2, m2c2 = -2.0f * c2;
      float bnvc[4];
#pragma unroll
      for (int n = 0; n < 4; ++n) bnvc[n] = bnv[n] * c2;
#pragma unroll
      for (int i = 0; i < 16; ++i) anv[i] *= c2;
#pragma unroll
      for (int m = 0; m < 4; ++m)
#pragma unroll
        for (int n = 0; n < 4; ++n)
#pragma unroll
          for (int r = 0; r < 4; ++r) {
            float arg = fmaf(acc[m][n][r], m2c2, anv[m * 4 + r] + bnvc[n]);
            float u = fast_exp2(arg);               // exp(d*base*0.5)
            float u2 = u * u;
            float a = fmaf(u, u, u);                // u + u^2
            float u4 = u2 * u2, u8 = u4 * u4;
            float b = fmaf(u8, u8, u8);             // u^8 + u^16
            s += a; s += u4; s += b;
          }
    } else {
      float sc[KK];
#pragma unroll
      for (int k = 0; k < KK; ++k) sc[k] = ctrl->scales[k];
#pragma unroll
      for (int m = 0; m < 4; ++m)
#pragma unroll
        for (int n = 0; n < 4; ++n)
#pragma unroll
          for (int r = 0; r < 4; ++r) {
            float d = (anv[m * 4 + r] + bnv[n]) - 2.0f * acc[m][n][r];
            float e = 0.f;
#pragma unroll
            for (int k = 0; k < KK; ++k) e += expf(d * sc[k]);
            s += e;
          }
    }
    // diagonal handled analytically in finalize
    double sd = (double)s;
#pragma unroll
    for (int off = 32; off > 0; off >>= 1) sd += __shfl_down(sd, off);
    double* wsum = (double*)smem;
    if ((t & 63) == 0) wsum[wid] = sd;
    __syncthreads();
    if (t == 0) atomicAdd(&S[sel], (wsum[0] + wsum[1]) + (wsum[2] + wsum[3]));
  }
}

// ---------------- fused radix round: grid hist + last-block scan ----------------
__global__ void __launch_bounds__(256)
radix_fused(Ctrl* __restrict__ ctrl, const float* __restrict__ buf,
            unsigned* __restrict__ gh, unsigned* __restrict__ tick,
            const float* __restrict__ ksc, int round, unsigned cap) {
  __shared__ unsigned h[256];
  __shared__ unsigned lastflag;
  int t = threadIdx.x;
  h[t] = 0;
  if (t == 0) lastflag = 0;
  __syncthreads();
  bool okw = window_ok(ctrl, cap);
  unsigned m = min(okw ? ctrl->wcount : ctrl->gcount, cap);
  unsigned pref = ctrl->spref;
  int shift = 24 - 8 * round;
  for (unsigned i = blockIdx.x * 256u + t; i < m; i += gridDim.x * 256u) {
    unsigned u = __float_as_uint(buf[i]);
    u ^= (u >> 31) ? 0xFFFFFFFFu : 0x80000000u;
    if (round == 0 || ((u ^ pref) >> (shift + 8)) == 0u)
      atomicAdd(&h[(u >> shift) & 255u], 1u);
  }
  __syncthreads();
  if (h[t]) atomicAdd(&gh[round * 256 + t], h[t]);
  __threadfence();
  if (t == 0)
    lastflag = (atomicAdd(&tick[round], 1u) == gridDim.x - 1u) ? 1u : 0u;
  __syncthreads();
  if (!lastflag) return;
  // last block scans this round's 256 bins
  unsigned rank = (round == 0) ? (okw ? RMED - ctrl->below : ctrl->rank) : ctrl->srank;
  unsigned c = atomicAdd(&gh[round * 256 + t], 0u);  // L2-forced read
  h[t] = c;
  __syncthreads();
  for (int off = 1; off < 256; off <<= 1) {
    unsigned v = h[t];
    unsigned add = (t >= off) ? h[t - off] : 0u;
    __syncthreads();
    h[t] = v + add;
    __syncthreads();
  }
  unsigned incl = h[t], excl = incl - c;
  if (rank >= excl && rank < incl) {
    unsigned np = pref | ((unsigned)t << shift);
    ctrl->spref = np;
    ctrl->srank = rank - excl;
    if (round == 3) {
      unsigned u = (np & 0x80000000u) ? (np ^ 0x80000000u) : ~np;
      float med = __uint_as_float(u) + 100.0f;  // undo d-100 store
      ctrl->median = med;
      float base = -1.0f / med;
#pragma unroll
      for (int k = 0; k < KK; ++k) ctrl->scales[k] = base * ksc[k];
      ctrl->c2 = base * 0.5f * 1.44269504088896f;
      ctrl->use_pow = (ksc[0] == 0.5f && ksc[1] == 1.0f && ksc[2] == 2.0f &&
                       ksc[3] == 4.0f && ksc[4] == 8.0f) ? 1u : 0u;
    }
  }
}

// ---------------- finalize ----------------
__global__ void finalize_kernel(const double* __restrict__ S, float* __restrict__ out) {
  if (threadIdx.x == 0 && blockIdx.x == 0) {
    double offd = 1.0 / ((double)NN * (double)(NN - 1));
    double invK = 1.0 / (double)KK;
    double kxx = (S[0] * invK) - (double)NN;  // subtract diagonal (exp(0)=1, KK terms)
    double kyy = (S[1] * invK) - (double)NN;
    double kzz = S[2] * invK;
    double val = offd * (kxx + kyy) - 2.0 * kzz / ((double)NN * (double)NN);
    out[0] = (float)val;
  }
}

extern "C" void kernel_launch(void* const* d_in, const int* in_sizes, int n_in,
                              void* d_out, int out_size, void* d_ws, size_t ws_size,
                              hipStream_t stream) {
  const float* x = (const float*)d_in[0];
  const float* y = (const float*)d_in[1];
  const float* ksc = (const float*)d_in[2];

  char* ws = (char*)d_ws;
  double* S = (double*)ws;                 // 3 doubles @ 0
  unsigned* hist = (unsigned*)(ws + 64);   // 1024 u32  @ 64
  unsigned* gh = (unsigned*)(ws + 4160);   // 4*256 u32 @ 4160
  unsigned* tick = (unsigned*)(ws + 8256); // 8 u32     @ 8256
  Ctrl* ctrl = (Ctrl*)(ws + 8288);         // ~64B      @ 8288
  float* xn = (float*)(ws + 8448);
  float* yn = xn + NN;                     // ends @ 41216
  const size_t SPL = (size_t)NN * DD * 2;  // 512KB per split array
  short* xhi = (short*)(ws + 65536);
  short* xlo = (short*)(ws + 65536 + SPL);
  short* yhi = (short*)(ws + 65536 + 2 * SPL);
  short* ylo = (short*)(ws + 65536 + 3 * SPL);
  size_t bufoff = 65536 + 4 * SPL;         // @ 2162688
  float* buf = (float*)(ws + bufoff);

  size_t avail = (ws_size > bufoff) ? (ws_size - bufoff) / 4 : 0;
  unsigned cap = (unsigned)((avail < (size_t)(8u << 20)) ? avail : (size_t)(8u << 20));
  // window around estimated median d~127.7; exact fallback covers a miss
  float loE, hiE;
  if (cap >= 1400000u)      { loE = 126.0f; hiE = 129.5f; }
  else if (cap >= 900000u)  { loE = 126.5f; hiE = 129.0f; }
  else if (cap >= 600000u)  { loE = 127.0f; hiE = 128.5f; }
  else                      { loE = 127.0f; hiE = 128.0f; }

  hipMemsetAsync(ws, 0, 8448, stream);  // S, hist, gh, tick, ctrl

  splitnorms_kernel<<<512, 256, 0, stream>>>(x, y, xhi, xlo, yhi, ylo, xn, yn);
  pair_kernel<0><<<dim3(32, 32), 256, 0, stream>>>(xhi, xlo, yhi, ylo, xn, yn, hist, ctrl,
                                                   buf, S, tick, loE, hiE, cap);
  pair_kernel<3><<<dim3(32, 32), 256, 0, stream>>>(xhi, xlo, yhi, ylo, xn, yn, hist, ctrl,
                                                   buf, S, tick, loE, hiE, cap);
  pair_kernel<1><<<dim3(32, 32), 256, 0, stream>>>(xhi, xlo, yhi, ylo, xn, yn, hist, ctrl,
                                                   buf, S, tick, loE, hiE, cap);
  for (int r = 0; r < 4; ++r)
    radix_fused<<<192, 256, 0, stream>>>(ctrl, buf, gh, tick, ksc, r, cap);
  pair_kernel<2><<<dim3(32, 32, 3), 256, 0, stream>>>(xhi, xlo, yhi, ylo, xn, yn, hist, ctrl,
                                                      buf, S, tick, loE, hiE, cap);
  finalize_kernel<<<1, 64, 0, stream>>>(S, (float*)d_out);
}